// Round 12
// baseline (1234.763 us; speedup 1.0000x reference)
//
#include <hip/hip_runtime.h>

#define HID 128
#define CELLS 98304
#define NE 250000
#define NSTEPS 2
#define NWIN 7814  // 2 * ceil(NE/64) 32-edge windows per edge type

typedef __attribute__((ext_vector_type(8))) short short8;
typedef __attribute__((ext_vector_type(4))) float f32x4;
typedef unsigned short u16;

// pi permutation: pi-slot s <-> natural col permf(s)
__device__ __forceinline__ int permf(int s) { return ((s & 7) << 4) | (s >> 3); }
// m storage position p: half = p>>6, lane = p&63,
// pi-slot = (lane>>2)*8 + half*4 + (lane&3); natural col = permf(slot)
__device__ __forceinline__ int nat_of_pos(int p) {
  int l = p & 63, hf = p >> 6;
  int slot = ((l >> 2) << 3) + (hf << 2) + (l & 3);
  return ((slot & 7) << 4) | (slot >> 3);
}

__device__ __forceinline__ u16 f2bf(float f) {
  unsigned int u = __builtin_bit_cast(unsigned int, f);
  u += 0x7fffu + ((u >> 16) & 1u);
  return (u16)(u >> 16);
}
__device__ __forceinline__ float bf2f(u16 s) {
  unsigned int u = ((unsigned int)s) << 16;
  return __builtin_bit_cast(float, u);
}
__device__ __forceinline__ float sigm(float x) { return 1.f / (1.f + __expf(-x)); }
__device__ __forceinline__ float tanha(float x) { return 1.f - 2.f / (__expf(2.f * x) + 1.f); }

// ---------------- prep: bf16-convert weights ----------------
__global__ void prep_kernel(
    const float* __restrict__ W0, const float* __restrict__ W1,
    const float* __restrict__ W2, const float* __restrict__ W3,
    const float* __restrict__ b0, const float* __restrict__ b1,
    const float* __restrict__ b2, const float* __restrict__ b3,
    const float* __restrict__ Wih, const float* __restrict__ Whh,
    const float* __restrict__ embed, const float* __restrict__ sw,
    u16* __restrict__ W0b, u16* __restrict__ W1b,
    u16* __restrict__ W2b, u16* __restrict__ W3b,
    u16* __restrict__ Wcb, float* __restrict__ bp,
    u16* __restrict__ embp, float* __restrict__ swp)
{
  int idx = blockIdx.x * 256 + threadIdx.x;
  if (idx < 65536) {  // W0b [et][n][k] natural (h is natural-ordered)
    W0b[idx] = f2bf(W0[idx]);
    return;
  }
  idx -= 65536;
  if (idx < 98304) {  // W1b/W2b/W3b [et][n][s]: K pi-permuted to match msg LDS tiles
    int which = idx >> 15, r = idx & 32767;
    int s = r & 127, n = (r >> 7) & 127, et = r >> 14;
    const float* W = which == 0 ? W1 : (which == 1 ? W2 : W3);
    u16* Wb = which == 0 ? W1b : (which == 1 ? W2b : W3b);
    Wb[r] = f2bf(W[(et * 128 + n) * 128 + permf(s)]);
    return;
  }
  idx -= 98304;
  if (idx < 262144) {  // Wcat [n=512][k=512] = [Wih(x|m0|m1)|Whh]; m-blocks K in m-storage order
    int s = idx & 511, n = idx >> 9;
    int blk = s >> 7, s7 = s & 127;
    int k7 = (blk == 1 || blk == 2) ? nat_of_pos(s7) : s7;  // x / rh natural
    float v = (blk < 3) ? Wih[n * 384 + blk * 128 + k7] : Whh[n * 128 + k7];
    Wcb[idx] = f2bf(v);
    return;
  }
  idx -= 262144;
  if (idx < 1024) {  // biases [layer 0..3][et][slot] pi-order
    int l = idx >> 8, r = idx & 255;
    int et = r >> 7, s = r & 127;
    const float* b = l == 0 ? b0 : (l == 1 ? b1 : (l == 2 ? b2 : b3));
    bp[idx] = b[et * 128 + permf(s)];
    return;
  }
  idx -= 1024;
  if (idx < 384) {  // embed natural bf16
    embp[idx] = f2bf(embed[idx]);
    return;
  }
  idx -= 384;
  if (idx < 128) swp[idx] = sw[idx];
}

// ---------------- init: x = embed[q] (natural, bf16), h = x (rc untouched:
// step 0 never reads it) ----------------
__global__ void init_kernel(const int* __restrict__ q, const u16* __restrict__ embp,
                            u16* __restrict__ xb, u16* __restrict__ h)
{
  int idx = blockIdx.x * 256 + threadIdx.x;
  int c = idx >> 7, s = idx & 127;
  u16 v = embp[q[c] * 128 + s];
  xb[idx] = v;
  h[idx] = v;
}

// ---------------- dst-sort pipeline: hist -> scan (2-level) -> scatter ----------------
__global__ void hist_kernel(const int* __restrict__ edst, int* __restrict__ counts)
{
  int idx = blockIdx.x * 256 + threadIdx.x;
  if (idx >= 2 * NE) return;
  int et = (idx >= NE) ? 1 : 0;
  atomicAdd(&counts[et * CELLS + edst[idx]], 1);
}

__global__ void scan1_kernel(const int* __restrict__ counts, int* __restrict__ S,
                             int* __restrict__ btot)
{
  __shared__ int sh[1024];
  const int t = threadIdx.x, b = blockIdx.x;
  const int i = b * 1024 + t;
  int v = counts[i];
  sh[t] = v;
  __syncthreads();
  int acc = v;
  for (int off = 1; off < 1024; off <<= 1) {
    int add = (t >= off) ? sh[t - off] : 0;
    __syncthreads();
    acc += add;
    sh[t] = acc;
    __syncthreads();
  }
  S[i] = acc - v;  // block-local exclusive
  if (t == 1023) btot[b] = acc;
}

__global__ void scan2_kernel(const int* __restrict__ btot, int* __restrict__ boffs,
                             int* __restrict__ S)
{
  __shared__ int sh[256];
  const int t = threadIdx.x;
  int v = (t < 192) ? btot[t] : 0;
  sh[t] = v;
  __syncthreads();
  int acc = v;
  for (int off = 1; off < 256; off <<= 1) {
    int add = (t >= off) ? sh[t - off] : 0;
    __syncthreads();
    acc += add;
    sh[t] = acc;
    __syncthreads();
  }
  if (t < 192) boffs[t] = acc - v;
  if (t == 0) S[2 * CELLS] = 2 * NE;
}

__global__ void scan3_kernel(int* __restrict__ S, const int* __restrict__ boffs)
{
  const int i = blockIdx.x * 1024 + threadIdx.x;
  S[i] += boffs[blockIdx.x];
}

__global__ void scatter_kernel(const int* __restrict__ esrc, const int* __restrict__ edst,
                               const int* __restrict__ S, int* __restrict__ fill,
                               int* __restrict__ ssrc, int* __restrict__ sdst)
{
  int idx = blockIdx.x * 256 + threadIdx.x;
  if (idx >= 2 * NE) return;
  int et = (idx >= NE) ? 1 : 0;
  int d = edst[idx];
  int pos = atomicAdd(&fill[et * CELLS + d], 1);
  int slot = S[et * CELLS + d] - et * NE + pos;  // et-local sorted slot
  sdst[et * NE + slot] = d;
  ssrc[et * NE + slot] = esrc[idx];
}

// bias + relu + pack-transpose into swizzled per-wave LDS A-tile (32 rows, pitch 128)
// slot c*8+nt holds natural col nt*16+c (= permf(c*8+nt))
__device__ __forceinline__ void bias_relu_store(f32x4 (&acc)[2][8], const float* __restrict__ bl,
                                                u16* __restrict__ ab, int q, int c)
{
  float bias[8];
  #pragma unroll
  for (int j = 0; j < 8; ++j) bias[j] = bl[c * 8 + j];
  #pragma unroll
  for (int mt = 0; mt < 2; ++mt) {
    #pragma unroll
    for (int r = 0; r < 4; ++r) {
      const int rowl = mt * 16 + 4 * q + r;
      short8 t;
      #pragma unroll
      for (int nt = 0; nt < 8; ++nt) {
        float v = acc[mt][nt][r] + bias[nt];
        v = v > 0.f ? v : 0.f;
        t[nt] = (short)f2bf(v);
      }
      *(short8*)(ab + rowl * 128 + ((c ^ (rowl & 15)) << 3)) = t;
    }
  }
}

// ---------------- fused 4-layer edge MLP + sorted segmented-sum scatter ----------------
// 2 waves x 32 PRIVATE edges (R5 window structure: 16 waves/CU, acc[2][8] = 64 AGPR),
// zero barriers. Epilogue = R10's: fp32 fab column scan; interior flush = 128B coalesced
// bf16 store; boundary flush -> fp32 partials to per-window side buffer. No atomics.
__launch_bounds__(128, 4)
__global__ void msg_kernel(
    const u16* __restrict__ h,
    const int* __restrict__ ssrc, const int* __restrict__ sdst,
    const int* __restrict__ S,
    const u16* __restrict__ W0b, const u16* __restrict__ W1b,
    const u16* __restrict__ W2b, const u16* __restrict__ W3b,
    const float* __restrict__ bp,
    u16* __restrict__ m0, u16* __restrict__ m1,
    int* __restrict__ side_dst, float* __restrict__ side_part)
{
  __shared__ u16 abuf[2][32 * 128];  // 8KB per wave, wave-private, XOR-swizzled
  const int et = blockIdx.y;
  const int tid = threadIdx.x;
  const int w = tid >> 6, lane = tid & 63, q = lane >> 4, c = lane & 15;
  const int ebase = blockIdx.x * 64 + w * 32;  // et-local sorted slot base for this wave
  const int win = blockIdx.x * 2 + w;
  const int* __restrict__ src = ssrc + et * NE;
  const int* __restrict__ dst = sdst + et * NE;
  const u16* __restrict__ Wl0 = W0b + et * 32768;
  const u16* __restrict__ Wl[3] = {W1b + et * 16384, W2b + et * 16384, W3b + et * 16384};
  u16* __restrict__ msgs = (et == 0) ? m0 : m1;
  u16* ab = abuf[w];

  int rowS[2], rowD[2];
  #pragma unroll
  for (int mt = 0; mt < 2; ++mt) {
    int e = ebase + mt * 16 + c;
    if (e >= NE) e = NE - 1;
    rowS[mt] = src[e];
    rowD[mt] = dst[e];
  }

  // run structure: lanes 0..31 carry edges. Cross-lane ops unconditional (round-3
  // lesson: exec-masked source lanes give undefined shuffle reads).
  const int eL = ebase + lane;
  const int dval = (lane < 32 && eL < NE) ? dst[eL] : -1;
  int rpS = 0, rpE = 0;
  if (dval >= 0) {
    rpS = S[et * CELLS + dval] - et * NE;
    rpE = S[et * CELLS + dval + 1] - et * NE;
  }
  const int dlagged = __shfl_up(dval, 1);          // all 64 lanes active
  const bool headp = (lane == 0) | (dval != dlagged);  // bitwise | : no control flow
  const unsigned long long tails =
      ((__ballot(headp) & 0xFFFFFFFFull) >> 1) | (1ull << 31);
  const unsigned long long intmask = __ballot(dval >= 0 && rpS >= ebase && rpE <= ebase + 32);

  const f32x4 zf = {0.f, 0.f, 0.f, 0.f};
  f32x4 acc[2][8];
  #pragma unroll
  for (int mt = 0; mt < 2; ++mt)
    #pragma unroll
    for (int nt = 0; nt < 8; ++nt) acc[mt][nt] = zf;

  // layer 0: K=256 = [h[src] | h[dst]] natural; A gathered straight from global h (16B/lane)
  #pragma unroll
  for (int ks = 0; ks < 8; ++ks) {
    const int kq = ks * 32 + q * 8;
    short8 a[2], b[8];
    #pragma unroll
    for (int mt = 0; mt < 2; ++mt) {
      int row = (ks < 4) ? rowS[mt] : rowD[mt];
      a[mt] = *(const short8*)(h + row * HID + (kq & 127));
    }
    #pragma unroll
    for (int nt = 0; nt < 8; ++nt)
      b[nt] = *(const short8*)(Wl0 + (nt * 16 + c) * 256 + kq);
    #pragma unroll
    for (int mt = 0; mt < 2; ++mt)
      #pragma unroll
      for (int nt = 0; nt < 8; ++nt)
        acc[mt][nt] = __builtin_amdgcn_mfma_f32_16x16x32_bf16(a[mt], b[nt], acc[mt][nt], 0, 0, 0);
  }
  bias_relu_store(acc, bp + et * 128, ab, q, c);

  // layers 1..3 (wave-private LDS round-trip; in-order DS => no barriers)
  #pragma unroll
  for (int l = 0; l < 3; ++l) {
    #pragma unroll
    for (int mt = 0; mt < 2; ++mt)
      #pragma unroll
      for (int nt = 0; nt < 8; ++nt) acc[mt][nt] = zf;
    #pragma unroll
    for (int ks = 0; ks < 4; ++ks) {
      const int kq = ks * 32 + q * 8;
      const int blk = ks * 4 + q;
      short8 a[2], b[8];
      #pragma unroll
      for (int mt = 0; mt < 2; ++mt) {
        const int row = mt * 16 + c;
        a[mt] = *(const short8*)(ab + row * 128 + ((blk ^ c) << 3));
      }
      #pragma unroll
      for (int nt = 0; nt < 8; ++nt)
        b[nt] = *(const short8*)(Wl[l] + (nt * 16 + c) * 128 + kq);
      #pragma unroll
      for (int mt = 0; mt < 2; ++mt)
        #pragma unroll
        for (int nt = 0; nt < 8; ++nt)
          acc[mt][nt] = __builtin_amdgcn_mfma_f32_16x16x32_bf16(a[mt], b[nt], acc[mt][nt], 0, 0, 0);
    }
    if (l < 2) bias_relu_store(acc, bp + (l + 1) * 256 + et * 128, ab, q, c);
  }

  // layer-3 epilogue: +bias into fp32 fab (two 64-feature passes over 32 rows), column
  // scan; interior flush = 128B coalesced bf16 store; boundary flush = fp32 partial.
  float bias[8];
  #pragma unroll
  for (int j = 0; j < 8; ++j) bias[j] = bp[3 * 256 + et * 128 + c * 8 + j];

  float* fab = (float*)ab;  // 32 rows x 64 feature-slots fp32 (8KB, wave-private)
  #pragma unroll
  for (int half = 0; half < 2; ++half) {
    #pragma unroll
    for (int mt = 0; mt < 2; ++mt) {
      #pragma unroll
      for (int r = 0; r < 4; ++r) {
        const int row = mt * 16 + 4 * q + r;
        f32x4 t;
        #pragma unroll
        for (int nti = 0; nti < 4; ++nti)
          t[nti] = acc[mt][half * 4 + nti][r] + bias[half * 4 + nti];
        *(f32x4*)(fab + row * 64 + c * 4) = t;
      }
    }
    float run = 0.f;
    int jstart = 0;
    #pragma unroll
    for (int j = 0; j < 32; ++j) {
      run += fab[j * 64 + lane];
      if ((tails >> j) & 1) {  // wave-uniform flush at run tail
        const int d = __builtin_amdgcn_readlane(dval, j);
        if (d >= 0) {
          if ((intmask >> j) & 1) {
            msgs[(size_t)d * HID + half * 64 + lane] = f2bf(run);
          } else {
            const int slot = (jstart == 0) ? 0 : 1;  // only first/last runs can straddle
            const size_t sb = ((size_t)et * NWIN + win) * 2 + slot;
            side_part[sb * 128 + half * 64 + lane] = run;
            if (lane == 0 && half == 0) side_dst[sb] = d;
          }
        }
        run = 0.f;
        jstart = j + 1;
      }
    }
  }
}

// ---------------- boundary fixup: owner window sums fp32 partials, writes bf16 m ------
__global__ void fixup_kernel(const int* __restrict__ S,
                             const int* __restrict__ side_dst,
                             const float* __restrict__ side_part,
                             u16* __restrict__ m0, u16* __restrict__ m1)
{
  const int b = blockIdx.x;           // et*NWIN + win
  const int et = b / NWIN, win = b - et * NWIN;
  const int t = threadIdx.x;          // 0..127
  u16* __restrict__ m = et ? m1 : m0;
  #pragma unroll
  for (int s = 0; s < 2; ++s) {
    const int d = side_dst[b * 2 + s];
    if (d < 0) continue;
    const int r0 = S[et * CELLS + d] - et * NE;
    if ((r0 >> 5) != win) continue;   // not the owner window (32-edge windows)
    const int w1 = (S[et * CELLS + d + 1] - et * NE - 1) >> 5;
    float sum = 0.f;
    for (int wi = win; wi <= w1; ++wi) {
      const int base = (et * NWIN + wi) * 2;
      if (side_dst[base + 0] == d) sum += side_part[(size_t)(base + 0) * 128 + t];
      if (side_dst[base + 1] == d) sum += side_part[(size_t)(base + 1) * 128 + t];
    }
    m[(size_t)d * HID + t] = f2bf(sum);
  }
}

// ---------------- fused LSTM: gates GEMM (K=512) + in-register activations + score -------
// block: 8 waves, 64 cells. Wave wf owns feature cols [wf*16, wf*16+16) for ALL 4 gates.
// rc is bf16; step 0 skips the rc read (known zero); final step skips rc/h writes.
__launch_bounds__(512, 4)
__global__ void lstm_kernel(
    const int step,
    const u16* __restrict__ xb, const u16* __restrict__ mm0, const u16* __restrict__ mm1,
    u16* __restrict__ h, u16* __restrict__ rc,
    const u16* __restrict__ Wcb, const float* __restrict__ swp,
    float* __restrict__ out)
{
  __shared__ u16 at[64 * 512];  // 64KB: A-tile, later reused for score partials
  const int tid = threadIdx.x;
  const int cb = blockIdx.x * 64;

  // stage A = [x | m0 | m1 | rh] bf16; m already bf16 in storage order (Wcb K matches)
  for (int base = tid * 8; base < 64 * 512; base += 4096) {
    const int cl = base >> 9, s = base & 511;
    const int cell = cb + cl;
    short8 t;
    if (s < 128) {
      t = *(const short8*)(xb + cell * 128 + s);
    } else if (s < 384) {
      const u16* mp = (s < 256 ? mm0 : mm1) + cell * 128 + (s & 127);
      t = *(const short8*)(mp);
    } else if (step == 0) {
      #pragma unroll
      for (int j = 0; j < 8; ++j) t[j] = 0;
    } else {
      t = *(const short8*)(h + cell * 128 + (s & 127));
    }
    const int blk = s >> 3;
    const int blks = (blk & 48) | ((blk ^ cl) & 15);
    *(short8*)(at + cl * 512 + blks * 8) = t;
  }
  __syncthreads();

  const int w = tid >> 6, lane = tid & 63, q = lane >> 4, c = lane & 15;
  const int wf = w;  // feature-16 group
  const f32x4 zf = {0.f, 0.f, 0.f, 0.f};
  f32x4 acc[4][4];  // [cell-tile][gate]
  #pragma unroll
  for (int mt = 0; mt < 4; ++mt)
    #pragma unroll
    for (int g = 0; g < 4; ++g) acc[mt][g] = zf;

  #pragma unroll
  for (int ks = 0; ks < 16; ++ks) {
    const int kq = ks * 32 + q * 8;
    const int blk = kq >> 3;
    short8 a[4], b[4];
    #pragma unroll
    for (int mt = 0; mt < 4; ++mt) {
      const int row = mt * 16 + c;
      const int blks = (blk & 48) | ((blk ^ c) & 15);
      a[mt] = *(const short8*)(at + row * 512 + blks * 8);
    }
    #pragma unroll
    for (int g = 0; g < 4; ++g)
      b[g] = *(const short8*)(Wcb + (g * 128 + wf * 16 + c) * 512 + kq);
    #pragma unroll
    for (int mt = 0; mt < 4; ++mt)
      #pragma unroll
      for (int g = 0; g < 4; ++g)
        acc[mt][g] = __builtin_amdgcn_mfma_f32_16x16x32_bf16(a[mt], b[g], acc[mt][g], 0, 0, 0);
  }
  __syncthreads();  // tile reads done everywhere; safe to reuse for score partials

  // in-register LSTM epilogue: lane (q,c) per (mt,r): cell = mt*16+4q+r, feat = wf*16+c
  const float swc = swp[wf * 16 + c];
  const bool last = (step == NSTEPS - 1);
  float* pt = (float*)at;  // [8 waves][64 cells] score partials
  #pragma unroll
  for (int mt = 0; mt < 4; ++mt) {
    #pragma unroll
    for (int r = 0; r < 4; ++r) {
      const int cl = mt * 16 + 4 * q + r;
      const int cell = cb + cl;
      const float ig = sigm(acc[mt][0][r]);
      const float fg = sigm(acc[mt][1][r]);
      const float gg = tanha(acc[mt][2][r]);
      const float og = sigm(acc[mt][3][r]);
      u16* rcp = rc + (size_t)cell * HID + wf * 16 + c;
      const float c0 = (step == 0) ? 0.f : bf2f(rcp[0]);
      const float nc = fg * c0 + ig * gg;
      const float nhv = og * tanha(nc);
      if (!last) {
        rcp[0] = f2bf(nc);
        h[(size_t)cell * HID + wf * 16 + c] = f2bf(nhv);
      }
      float v = nhv * swc;  // score partial, reduce over c (16 feats)
      v += __shfl_xor(v, 1); v += __shfl_xor(v, 2);
      v += __shfl_xor(v, 4); v += __shfl_xor(v, 8);
      if (c == 0) pt[wf * 64 + cl] = v;
    }
  }
  __syncthreads();
  if (tid < 64) {
    float s = 0.f;
    #pragma unroll
    for (int ww = 0; ww < 8; ++ww) s += pt[ww * 64 + tid];
    out[step * CELLS + cb + tid] = s;
  }
}

extern "C" void kernel_launch(void* const* d_in, const int* in_sizes, int n_in,
                              void* d_out, int out_size, void* d_ws, size_t ws_size,
                              hipStream_t stream)
{
  const int* q      = (const int*)d_in[0];
  const int* esrc   = (const int*)d_in[1];
  const int* edst   = (const int*)d_in[2];
  const float* embed= (const float*)d_in[3];
  const float* W0   = (const float*)d_in[4];
  const float* b0   = (const float*)d_in[5];
  const float* W1   = (const float*)d_in[6];
  const float* b1   = (const float*)d_in[7];
  const float* W2   = (const float*)d_in[8];
  const float* b2   = (const float*)d_in[9];
  const float* W3   = (const float*)d_in[10];
  const float* b3   = (const float*)d_in[11];
  const float* Wih  = (const float*)d_in[12];
  const float* Whh  = (const float*)d_in[13];
  const float* sw   = (const float*)d_in[14];

  char* ws = (char*)d_ws;
  size_t off = 0;
  auto alloc = [&](size_t bytes) {
    void* p = ws + off;
    off += (bytes + 255) & ~(size_t)255;
    return p;
  };
  u16*   h    = (u16*)  alloc((size_t)CELLS * HID * 2);
  u16*   xb   = (u16*)  alloc((size_t)CELLS * HID * 2);
  u16*   rc   = (u16*)  alloc((size_t)CELLS * HID * 2);  // bf16 carry
  u16*   m0   = (u16*)  alloc((size_t)CELLS * HID * 2);  // bf16; m1 contiguous after
  u16*   m1   = (u16*)  alloc((size_t)CELLS * HID * 2);
  u16*   W0b  = (u16*)  alloc(2 * 128 * 256 * 2);
  u16*   W1b  = (u16*)  alloc(2 * 128 * 128 * 2);
  u16*   W2b  = (u16*)  alloc(2 * 128 * 128 * 2);
  u16*   W3b  = (u16*)  alloc(2 * 128 * 128 * 2);
  u16*   Wcb  = (u16*)  alloc(512 * 512 * 2);
  float* bp   = (float*)alloc(4 * 256 * 4);
  u16*   embp = (u16*)  alloc(384 * 2);
  float* swp  = (float*)alloc(128 * 4);
  // sort workspace
  int*   counts = (int*)alloc((size_t)2 * CELLS * 4);
  int*   Sarr   = (int*)alloc(((size_t)2 * CELLS + 1) * 4);
  int*   fill   = (int*)alloc((size_t)2 * CELLS * 4);
  int*   btot   = (int*)alloc(192 * 4);
  int*   boffs  = (int*)alloc(192 * 4);
  int*   ssrc   = (int*)alloc((size_t)2 * NE * 4);
  int*   sdst   = (int*)alloc((size_t)2 * NE * 4);
  // boundary side buffers
  int*   side_dst  = (int*)  alloc((size_t)2 * NWIN * 2 * 4);
  float* side_part = (float*)alloc((size_t)2 * NWIN * 2 * 128 * 4);

  prep_kernel<<<1670, 256, 0, stream>>>(W0, W1, W2, W3, b0, b1, b2, b3, Wih, Whh, embed, sw,
                                        W0b, W1b, W2b, W3b, Wcb, bp, embp, swp);
  init_kernel<<<(CELLS * HID) / 256, 256, 0, stream>>>(q, embp, xb, h);

  // dst-sort both edge types
  hipMemsetAsync(counts, 0, (size_t)2 * CELLS * 4, stream);
  hipMemsetAsync(fill, 0, (size_t)2 * CELLS * 4, stream);
  hist_kernel<<<(2 * NE + 255) / 256, 256, 0, stream>>>(edst, counts);
  scan1_kernel<<<192, 1024, 0, stream>>>(counts, Sarr, btot);
  scan2_kernel<<<1, 256, 0, stream>>>(btot, boffs, Sarr);
  scan3_kernel<<<192, 1024, 0, stream>>>(Sarr, boffs);
  scatter_kernel<<<(2 * NE + 255) / 256, 256, 0, stream>>>(esrc, edst, Sarr, fill, ssrc, sdst);

  for (int step = 0; step < NSTEPS; ++step) {
    hipMemsetAsync(m0, 0, (size_t)2 * CELLS * HID * 2, stream);      // m0+m1 (bf16)
    hipMemsetAsync(side_dst, 0xFF, (size_t)2 * NWIN * 2 * 4, stream);  // dst = -1
    msg_kernel<<<dim3((NE + 63) / 64, 2), 128, 0, stream>>>(h, ssrc, sdst, Sarr,
                                                            W0b, W1b, W2b, W3b, bp,
                                                            m0, m1, side_dst, side_part);
    fixup_kernel<<<2 * NWIN, 128, 0, stream>>>(Sarr, side_dst, side_part, m0, m1);
    lstm_kernel<<<CELLS / 64, 512, 0, stream>>>(step, xb, m0, m1, h, rc, Wcb, swp, (float*)d_out);
  }
}

// Round 13
// 851.105 us; speedup vs baseline: 1.4508x; 1.4508x over previous
//
#include <hip/hip_runtime.h>

#define HID 128
#define CELLS 98304
#define NE 250000
#define NSTEPS 2
#define NWIN 3908  // ceil(NE/64) 64-edge windows per edge type (rounded to block pairs)

typedef __attribute__((ext_vector_type(8))) short short8;
typedef __attribute__((ext_vector_type(4))) float f32x4;
typedef unsigned short u16;

// pi permutation: pi-slot s <-> natural col permf(s)
__device__ __forceinline__ int permf(int s) { return ((s & 7) << 4) | (s >> 3); }
// m storage position p: half = p>>6, lane = p&63,
// pi-slot = (lane>>2)*8 + half*4 + (lane&3); natural col = permf(slot)
__device__ __forceinline__ int nat_of_pos(int p) {
  int l = p & 63, hf = p >> 6;
  int slot = ((l >> 2) << 3) + (hf << 2) + (l & 3);
  return ((slot & 7) << 4) | (slot >> 3);
}

__device__ __forceinline__ u16 f2bf(float f) {
  unsigned int u = __builtin_bit_cast(unsigned int, f);
  u += 0x7fffu + ((u >> 16) & 1u);
  return (u16)(u >> 16);
}
__device__ __forceinline__ float bf2f(u16 s) {
  unsigned int u = ((unsigned int)s) << 16;
  return __builtin_bit_cast(float, u);
}
__device__ __forceinline__ float sigm(float x) { return 1.f / (1.f + __expf(-x)); }
__device__ __forceinline__ float tanha(float x) { return 1.f - 2.f / (__expf(2.f * x) + 1.f); }

// ---------------- prep: bf16-convert weights ----------------
__global__ void prep_kernel(
    const float* __restrict__ W0, const float* __restrict__ W1,
    const float* __restrict__ W2, const float* __restrict__ W3,
    const float* __restrict__ b0, const float* __restrict__ b1,
    const float* __restrict__ b2, const float* __restrict__ b3,
    const float* __restrict__ Wih, const float* __restrict__ Whh,
    const float* __restrict__ embed, const float* __restrict__ sw,
    u16* __restrict__ W0b, u16* __restrict__ W1b,
    u16* __restrict__ W2b, u16* __restrict__ W3b,
    u16* __restrict__ Wcb, float* __restrict__ bp,
    u16* __restrict__ embp, float* __restrict__ swp)
{
  int idx = blockIdx.x * 256 + threadIdx.x;
  if (idx < 65536) {  // W0b [et][n][k] natural (h is natural-ordered)
    W0b[idx] = f2bf(W0[idx]);
    return;
  }
  idx -= 65536;
  if (idx < 98304) {  // W1b/W2b/W3b [et][n][s]: K pi-permuted to match msg LDS tiles
    int which = idx >> 15, r = idx & 32767;
    int s = r & 127, n = (r >> 7) & 127, et = r >> 14;
    const float* W = which == 0 ? W1 : (which == 1 ? W2 : W3);
    u16* Wb = which == 0 ? W1b : (which == 1 ? W2b : W3b);
    Wb[r] = f2bf(W[(et * 128 + n) * 128 + permf(s)]);
    return;
  }
  idx -= 98304;
  if (idx < 262144) {  // Wcat [n=512][k=512] = [Wih(x|m0|m1)|Whh]; m-blocks K in m-storage order
    int s = idx & 511, n = idx >> 9;
    int blk = s >> 7, s7 = s & 127;
    int k7 = (blk == 1 || blk == 2) ? nat_of_pos(s7) : s7;  // x / rh natural
    float v = (blk < 3) ? Wih[n * 384 + blk * 128 + k7] : Whh[n * 128 + k7];
    Wcb[idx] = f2bf(v);
    return;
  }
  idx -= 262144;
  if (idx < 1024) {  // biases [layer 0..3][et][slot] pi-order
    int l = idx >> 8, r = idx & 255;
    int et = r >> 7, s = r & 127;
    const float* b = l == 0 ? b0 : (l == 1 ? b1 : (l == 2 ? b2 : b3));
    bp[idx] = b[et * 128 + permf(s)];
    return;
  }
  idx -= 1024;
  if (idx < 384) {  // embed natural bf16
    embp[idx] = f2bf(embed[idx]);
    return;
  }
  idx -= 384;
  if (idx < 128) swp[idx] = sw[idx];
}

// ---------------- init: x = embed[q] (natural, bf16), h = x (rc untouched:
// step 0 never reads it) ----------------
__global__ void init_kernel(const int* __restrict__ q, const u16* __restrict__ embp,
                            u16* __restrict__ xb, u16* __restrict__ h)
{
  int idx = blockIdx.x * 256 + threadIdx.x;
  int c = idx >> 7, s = idx & 127;
  u16 v = embp[q[c] * 128 + s];
  xb[idx] = v;
  h[idx] = v;
}

// ---------------- dst-sort pipeline: hist -> scan (2-level) -> scatter ----------------
__global__ void hist_kernel(const int* __restrict__ edst, int* __restrict__ counts)
{
  int idx = blockIdx.x * 256 + threadIdx.x;
  if (idx >= 2 * NE) return;
  int et = (idx >= NE) ? 1 : 0;
  atomicAdd(&counts[et * CELLS + edst[idx]], 1);
}

__global__ void scan1_kernel(const int* __restrict__ counts, int* __restrict__ S,
                             int* __restrict__ btot)
{
  __shared__ int sh[1024];
  const int t = threadIdx.x, b = blockIdx.x;
  const int i = b * 1024 + t;
  int v = counts[i];
  sh[t] = v;
  __syncthreads();
  int acc = v;
  for (int off = 1; off < 1024; off <<= 1) {
    int add = (t >= off) ? sh[t - off] : 0;
    __syncthreads();
    acc += add;
    sh[t] = acc;
    __syncthreads();
  }
  S[i] = acc - v;  // block-local exclusive
  if (t == 1023) btot[b] = acc;
}

__global__ void scan2_kernel(const int* __restrict__ btot, int* __restrict__ boffs,
                             int* __restrict__ S)
{
  __shared__ int sh[256];
  const int t = threadIdx.x;
  int v = (t < 192) ? btot[t] : 0;
  sh[t] = v;
  __syncthreads();
  int acc = v;
  for (int off = 1; off < 256; off <<= 1) {
    int add = (t >= off) ? sh[t - off] : 0;
    __syncthreads();
    acc += add;
    sh[t] = acc;
    __syncthreads();
  }
  if (t < 192) boffs[t] = acc - v;
  if (t == 0) S[2 * CELLS] = 2 * NE;
}

__global__ void scan3_kernel(int* __restrict__ S, const int* __restrict__ boffs)
{
  const int i = blockIdx.x * 1024 + threadIdx.x;
  S[i] += boffs[blockIdx.x];
}

__global__ void scatter_kernel(const int* __restrict__ esrc, const int* __restrict__ edst,
                               const int* __restrict__ S, int* __restrict__ fill,
                               int* __restrict__ ssrc, int* __restrict__ sdst)
{
  int idx = blockIdx.x * 256 + threadIdx.x;
  if (idx >= 2 * NE) return;
  int et = (idx >= NE) ? 1 : 0;
  int d = edst[idx];
  int pos = atomicAdd(&fill[et * CELLS + d], 1);
  int slot = S[et * CELLS + d] - et * NE + pos;  // et-local sorted slot
  sdst[et * NE + slot] = d;
  ssrc[et * NE + slot] = esrc[idx];
}

// bias + relu + pack-transpose into swizzled per-wave LDS A-tile (pitch 128, 8-col XOR swizzle)
__device__ __forceinline__ void bias_relu_store(f32x4 (&acc)[4][8], const float* __restrict__ bl,
                                                u16* __restrict__ ab, int q, int c)
{
  float bias[8];
  #pragma unroll
  for (int j = 0; j < 8; ++j) bias[j] = bl[c * 8 + j];
  #pragma unroll
  for (int mt = 0; mt < 4; ++mt) {
    #pragma unroll
    for (int r = 0; r < 4; ++r) {
      const int rowl = mt * 16 + 4 * q + r;
      short8 t;
      #pragma unroll
      for (int nt = 0; nt < 8; ++nt) {
        float v = acc[mt][nt][r] + bias[nt];
        v = v > 0.f ? v : 0.f;
        t[nt] = (short)f2bf(v);
      }
      *(short8*)(ab + rowl * 128 + ((c ^ (rowl & 15)) << 3)) = t;
    }
  }
}

// ---------------- fused 4-layer edge MLP + sorted segmented-sum scatter ----------------
// 2 private 64-edge windows/block, zero barriers, fab epilogue. m is bf16; interior runs
// plain 128B store; boundary runs -> fp32 partials to per-window side buffer. No atomics.
// NOTE (R5/R12 lesson): do NOT raise min-waves here — acc[4][8]+operands need the full
// 256-reg budget; forcing 4 waves/SIMD spills to scratch (+330MB WRITE, +160MB FETCH).
__launch_bounds__(128, 2)
__global__ void msg_kernel(
    const u16* __restrict__ h,
    const int* __restrict__ ssrc, const int* __restrict__ sdst,
    const int* __restrict__ S,
    const u16* __restrict__ W0b, const u16* __restrict__ W1b,
    const u16* __restrict__ W2b, const u16* __restrict__ W3b,
    const float* __restrict__ bp,
    u16* __restrict__ m0, u16* __restrict__ m1,
    int* __restrict__ side_dst, float* __restrict__ side_part)
{
  __shared__ u16 abuf[2][64 * 128];  // 32KB, per-wave private, XOR-swizzled
  const int et = blockIdx.y;
  const int tid = threadIdx.x;
  const int w = tid >> 6, lane = tid & 63, q = lane >> 4, c = lane & 15;
  const int ebase = blockIdx.x * 128 + w * 64;  // et-local sorted slot base for this wave
  const int win = blockIdx.x * 2 + w;
  const int* __restrict__ src = ssrc + et * NE;
  const int* __restrict__ dst = sdst + et * NE;
  const u16* __restrict__ Wl0 = W0b + et * 32768;
  const u16* __restrict__ Wl[3] = {W1b + et * 16384, W2b + et * 16384, W3b + et * 16384};
  u16* __restrict__ msgs = (et == 0) ? m0 : m1;
  u16* ab = abuf[w];

  int rowS[4], rowD[4];
  #pragma unroll
  for (int mt = 0; mt < 4; ++mt) {
    int e = ebase + mt * 16 + c;
    if (e >= NE) e = NE - 1;
    rowS[mt] = src[e];
    rowD[mt] = dst[e];
  }

  // run structure (wave-uniform masks). Cross-lane ops unconditional (round-3 lesson:
  // exec-masked source lanes give undefined shuffle reads).
  const int eL = ebase + lane;
  const int dval = (eL < NE) ? dst[eL] : -1;
  int rpS = 0, rpE = 0;
  if (dval >= 0) {
    rpS = S[et * CELLS + dval] - et * NE;
    rpE = S[et * CELLS + dval + 1] - et * NE;
  }
  const int dlagged = __shfl_up(dval, 1);          // all 64 lanes active
  const bool headp = (lane == 0) | (dval != dlagged);  // bitwise | : no control flow
  const unsigned long long tails = (__ballot(headp) >> 1) | (1ull << 63);
  const unsigned long long intmask = __ballot(dval >= 0 && rpS >= ebase && rpE <= ebase + 64);

  const f32x4 zf = {0.f, 0.f, 0.f, 0.f};
  f32x4 acc[4][8];
  #pragma unroll
  for (int mt = 0; mt < 4; ++mt)
    #pragma unroll
    for (int nt = 0; nt < 8; ++nt) acc[mt][nt] = zf;

  // layer 0: K=256 = [h[src] | h[dst]] natural; A gathered straight from global h (16B/lane)
  #pragma unroll
  for (int ks = 0; ks < 8; ++ks) {
    const int kq = ks * 32 + q * 8;
    short8 a[4], b[8];
    #pragma unroll
    for (int mt = 0; mt < 4; ++mt) {
      int row = (ks < 4) ? rowS[mt] : rowD[mt];
      a[mt] = *(const short8*)(h + row * HID + (kq & 127));
    }
    #pragma unroll
    for (int nt = 0; nt < 8; ++nt)
      b[nt] = *(const short8*)(Wl0 + (nt * 16 + c) * 256 + kq);
    #pragma unroll
    for (int mt = 0; mt < 4; ++mt)
      #pragma unroll
      for (int nt = 0; nt < 8; ++nt)
        acc[mt][nt] = __builtin_amdgcn_mfma_f32_16x16x32_bf16(a[mt], b[nt], acc[mt][nt], 0, 0, 0);
  }
  bias_relu_store(acc, bp + et * 128, ab, q, c);

  // layers 1..3 (wave-private LDS round-trip; in-order DS => no barriers)
  #pragma unroll
  for (int l = 0; l < 3; ++l) {
    #pragma unroll
    for (int mt = 0; mt < 4; ++mt)
      #pragma unroll
      for (int nt = 0; nt < 8; ++nt) acc[mt][nt] = zf;
    #pragma unroll
    for (int ks = 0; ks < 4; ++ks) {
      const int kq = ks * 32 + q * 8;
      const int blk = ks * 4 + q;
      short8 a[4], b[8];
      #pragma unroll
      for (int mt = 0; mt < 4; ++mt) {
        const int row = mt * 16 + c;
        a[mt] = *(const short8*)(ab + row * 128 + ((blk ^ c) << 3));
      }
      #pragma unroll
      for (int nt = 0; nt < 8; ++nt)
        b[nt] = *(const short8*)(Wl[l] + (nt * 16 + c) * 128 + kq);
      #pragma unroll
      for (int mt = 0; mt < 4; ++mt)
        #pragma unroll
        for (int nt = 0; nt < 8; ++nt)
          acc[mt][nt] = __builtin_amdgcn_mfma_f32_16x16x32_bf16(a[mt], b[nt], acc[mt][nt], 0, 0, 0);
    }
    if (l < 2) bias_relu_store(acc, bp + (l + 1) * 256 + et * 128, ab, q, c);
  }

  // layer-3 epilogue: +bias into fp32 fab (two 64-feature passes), column scan; interior
  // flush = 128B coalesced bf16 store; boundary flush = fp32 partial to side buffer.
  float bias[8];
  #pragma unroll
  for (int j = 0; j < 8; ++j) bias[j] = bp[3 * 256 + et * 128 + c * 8 + j];

  float* fab = (float*)ab;  // 64 rows x 64 feature-slots fp32 (16KB, wave-private)
  #pragma unroll
  for (int half = 0; half < 2; ++half) {
    #pragma unroll
    for (int mt = 0; mt < 4; ++mt) {
      #pragma unroll
      for (int r = 0; r < 4; ++r) {
        const int row = mt * 16 + 4 * q + r;
        f32x4 t;
        #pragma unroll
        for (int nti = 0; nti < 4; ++nti)
          t[nti] = acc[mt][half * 4 + nti][r] + bias[half * 4 + nti];
        *(f32x4*)(fab + row * 64 + c * 4) = t;
      }
    }
    float run = 0.f;
    int jstart = 0;
    #pragma unroll
    for (int j = 0; j < 64; ++j) {
      run += fab[j * 64 + lane];
      if ((tails >> j) & 1) {  // wave-uniform flush at run tail
        const int d = __builtin_amdgcn_readlane(dval, j);
        if (d >= 0) {
          if ((intmask >> j) & 1) {
            msgs[(size_t)d * HID + half * 64 + lane] = f2bf(run);
          } else {
            const int slot = (jstart == 0) ? 0 : 1;  // only first/last runs can straddle
            const size_t sb = ((size_t)et * NWIN + win) * 2 + slot;
            side_part[sb * 128 + half * 64 + lane] = run;
            if (lane == 0 && half == 0) side_dst[sb] = d;
          }
        }
        run = 0.f;
        jstart = j + 1;
      }
    }
  }
}

// ---------------- boundary fixup: owner window sums fp32 partials, writes bf16 m ------
__global__ void fixup_kernel(const int* __restrict__ S,
                             const int* __restrict__ side_dst,
                             const float* __restrict__ side_part,
                             u16* __restrict__ m0, u16* __restrict__ m1)
{
  const int b = blockIdx.x;           // et*NWIN + win
  const int et = b / NWIN, win = b - et * NWIN;
  const int t = threadIdx.x;          // 0..127
  u16* __restrict__ m = et ? m1 : m0;
  #pragma unroll
  for (int s = 0; s < 2; ++s) {
    const int d = side_dst[b * 2 + s];
    if (d < 0) continue;
    const int r0 = S[et * CELLS + d] - et * NE;
    if ((r0 >> 6) != win) continue;   // not the owner window (64-edge windows)
    const int w1 = (S[et * CELLS + d + 1] - et * NE - 1) >> 6;
    float sum = 0.f;
    for (int wi = win; wi <= w1; ++wi) {
      const int base = (et * NWIN + wi) * 2;
      if (side_dst[base + 0] == d) sum += side_part[(size_t)(base + 0) * 128 + t];
      if (side_dst[base + 1] == d) sum += side_part[(size_t)(base + 1) * 128 + t];
    }
    m[(size_t)d * HID + t] = f2bf(sum);
  }
}

// ---------------- fused LSTM: gates GEMM (K=512) + in-register activations + score -------
// block: 8 waves, 64 cells. Wave wf owns feature cols [wf*16, wf*16+16) for ALL 4 gates.
// rc is bf16; step 0 skips the rc read (known zero); final step skips rc/h writes.
__launch_bounds__(512, 4)
__global__ void lstm_kernel(
    const int step,
    const u16* __restrict__ xb, const u16* __restrict__ mm0, const u16* __restrict__ mm1,
    u16* __restrict__ h, u16* __restrict__ rc,
    const u16* __restrict__ Wcb, const float* __restrict__ swp,
    float* __restrict__ out)
{
  __shared__ u16 at[64 * 512];  // 64KB: A-tile, later reused for score partials
  const int tid = threadIdx.x;
  const int cb = blockIdx.x * 64;

  // stage A = [x | m0 | m1 | rh] bf16; m already bf16 in storage order (Wcb K matches)
  for (int base = tid * 8; base < 64 * 512; base += 4096) {
    const int cl = base >> 9, s = base & 511;
    const int cell = cb + cl;
    short8 t;
    if (s < 128) {
      t = *(const short8*)(xb + cell * 128 + s);
    } else if (s < 384) {
      const u16* mp = (s < 256 ? mm0 : mm1) + cell * 128 + (s & 127);
      t = *(const short8*)(mp);
    } else if (step == 0) {
      #pragma unroll
      for (int j = 0; j < 8; ++j) t[j] = 0;
    } else {
      t = *(const short8*)(h + cell * 128 + (s & 127));
    }
    const int blk = s >> 3;
    const int blks = (blk & 48) | ((blk ^ cl) & 15);
    *(short8*)(at + cl * 512 + blks * 8) = t;
  }
  __syncthreads();

  const int w = tid >> 6, lane = tid & 63, q = lane >> 4, c = lane & 15;
  const int wf = w;  // feature-16 group
  const f32x4 zf = {0.f, 0.f, 0.f, 0.f};
  f32x4 acc[4][4];  // [cell-tile][gate]
  #pragma unroll
  for (int mt = 0; mt < 4; ++mt)
    #pragma unroll
    for (int g = 0; g < 4; ++g) acc[mt][g] = zf;

  #pragma unroll
  for (int ks = 0; ks < 16; ++ks) {
    const int kq = ks * 32 + q * 8;
    const int blk = kq >> 3;
    short8 a[4], b[4];
    #pragma unroll
    for (int mt = 0; mt < 4; ++mt) {
      const int row = mt * 16 + c;
      const int blks = (blk & 48) | ((blk ^ c) & 15);
      a[mt] = *(const short8*)(at + row * 512 + blks * 8);
    }
    #pragma unroll
    for (int g = 0; g < 4; ++g)
      b[g] = *(const short8*)(Wcb + (g * 128 + wf * 16 + c) * 512 + kq);
    #pragma unroll
    for (int mt = 0; mt < 4; ++mt)
      #pragma unroll
      for (int g = 0; g < 4; ++g)
        acc[mt][g] = __builtin_amdgcn_mfma_f32_16x16x32_bf16(a[mt], b[g], acc[mt][g], 0, 0, 0);
  }
  __syncthreads();  // tile reads done everywhere; safe to reuse for score partials

  // in-register LSTM epilogue: lane (q,c) per (mt,r): cell = mt*16+4q+r, feat = wf*16+c
  const float swc = swp[wf * 16 + c];
  const bool last = (step == NSTEPS - 1);
  float* pt = (float*)at;  // [8 waves][64 cells] score partials
  #pragma unroll
  for (int mt = 0; mt < 4; ++mt) {
    #pragma unroll
    for (int r = 0; r < 4; ++r) {
      const int cl = mt * 16 + 4 * q + r;
      const int cell = cb + cl;
      const float ig = sigm(acc[mt][0][r]);
      const float fg = sigm(acc[mt][1][r]);
      const float gg = tanha(acc[mt][2][r]);
      const float og = sigm(acc[mt][3][r]);
      u16* rcp = rc + (size_t)cell * HID + wf * 16 + c;
      const float c0 = (step == 0) ? 0.f : bf2f(rcp[0]);
      const float nc = fg * c0 + ig * gg;
      const float nhv = og * tanha(nc);
      if (!last) {
        rcp[0] = f2bf(nc);
        h[(size_t)cell * HID + wf * 16 + c] = f2bf(nhv);
      }
      float v = nhv * swc;  // score partial, reduce over c (16 feats)
      v += __shfl_xor(v, 1); v += __shfl_xor(v, 2);
      v += __shfl_xor(v, 4); v += __shfl_xor(v, 8);
      if (c == 0) pt[wf * 64 + cl] = v;
    }
  }
  __syncthreads();
  if (tid < 64) {
    float s = 0.f;
    #pragma unroll
    for (int ww = 0; ww < 8; ++ww) s += pt[ww * 64 + tid];
    out[step * CELLS + cb + tid] = s;
  }
}

extern "C" void kernel_launch(void* const* d_in, const int* in_sizes, int n_in,
                              void* d_out, int out_size, void* d_ws, size_t ws_size,
                              hipStream_t stream)
{
  const int* q      = (const int*)d_in[0];
  const int* esrc   = (const int*)d_in[1];
  const int* edst   = (const int*)d_in[2];
  const float* embed= (const float*)d_in[3];
  const float* W0   = (const float*)d_in[4];
  const float* b0   = (const float*)d_in[5];
  const float* W1   = (const float*)d_in[6];
  const float* b1   = (const float*)d_in[7];
  const float* W2   = (const float*)d_in[8];
  const float* b2   = (const float*)d_in[9];
  const float* W3   = (const float*)d_in[10];
  const float* b3   = (const float*)d_in[11];
  const float* Wih  = (const float*)d_in[12];
  const float* Whh  = (const float*)d_in[13];
  const float* sw   = (const float*)d_in[14];

  char* ws = (char*)d_ws;
  size_t off = 0;
  auto alloc = [&](size_t bytes) {
    void* p = ws + off;
    off += (bytes + 255) & ~(size_t)255;
    return p;
  };
  u16*   h    = (u16*)  alloc((size_t)CELLS * HID * 2);
  u16*   xb   = (u16*)  alloc((size_t)CELLS * HID * 2);
  u16*   rc   = (u16*)  alloc((size_t)CELLS * HID * 2);  // bf16 carry
  u16*   m0   = (u16*)  alloc((size_t)CELLS * HID * 2);  // bf16; m1 contiguous after
  u16*   m1   = (u16*)  alloc((size_t)CELLS * HID * 2);
  u16*   W0b  = (u16*)  alloc(2 * 128 * 256 * 2);
  u16*   W1b  = (u16*)  alloc(2 * 128 * 128 * 2);
  u16*   W2b  = (u16*)  alloc(2 * 128 * 128 * 2);
  u16*   W3b  = (u16*)  alloc(2 * 128 * 128 * 2);
  u16*   Wcb  = (u16*)  alloc(512 * 512 * 2);
  float* bp   = (float*)alloc(4 * 256 * 4);
  u16*   embp = (u16*)  alloc(384 * 2);
  float* swp  = (float*)alloc(128 * 4);
  // sort workspace
  int*   counts = (int*)alloc((size_t)2 * CELLS * 4);
  int*   Sarr   = (int*)alloc(((size_t)2 * CELLS + 1) * 4);
  int*   fill   = (int*)alloc((size_t)2 * CELLS * 4);
  int*   btot   = (int*)alloc(192 * 4);
  int*   boffs  = (int*)alloc(192 * 4);
  int*   ssrc   = (int*)alloc((size_t)2 * NE * 4);
  int*   sdst   = (int*)alloc((size_t)2 * NE * 4);
  // boundary side buffers
  int*   side_dst  = (int*)  alloc((size_t)2 * NWIN * 2 * 4);
  float* side_part = (float*)alloc((size_t)2 * NWIN * 2 * 128 * 4);

  prep_kernel<<<1670, 256, 0, stream>>>(W0, W1, W2, W3, b0, b1, b2, b3, Wih, Whh, embed, sw,
                                        W0b, W1b, W2b, W3b, Wcb, bp, embp, swp);
  init_kernel<<<(CELLS * HID) / 256, 256, 0, stream>>>(q, embp, xb, h);

  // dst-sort both edge types
  hipMemsetAsync(counts, 0, (size_t)2 * CELLS * 4, stream);
  hipMemsetAsync(fill, 0, (size_t)2 * CELLS * 4, stream);
  hist_kernel<<<(2 * NE + 255) / 256, 256, 0, stream>>>(edst, counts);
  scan1_kernel<<<192, 1024, 0, stream>>>(counts, Sarr, btot);
  scan2_kernel<<<1, 256, 0, stream>>>(btot, boffs, Sarr);
  scan3_kernel<<<192, 1024, 0, stream>>>(Sarr, boffs);
  scatter_kernel<<<(2 * NE + 255) / 256, 256, 0, stream>>>(esrc, edst, Sarr, fill, ssrc, sdst);

  // m zeroing hoisted out of the step loop: every dst with >=1 edge gets its full row
  // rewritten each step (interior flush or fixup); zero-degree rows stay zero. side_dst
  // values are step-invariant (same sorted graph), so one 0xFF fill suffices.
  hipMemsetAsync(m0, 0, (size_t)2 * CELLS * HID * 2, stream);        // m0+m1 (bf16)
  hipMemsetAsync(side_dst, 0xFF, (size_t)2 * NWIN * 2 * 4, stream);  // dst = -1

  for (int step = 0; step < NSTEPS; ++step) {
    msg_kernel<<<dim3((NE + 127) / 128, 2), 128, 0, stream>>>(h, ssrc, sdst, Sarr,
                                                              W0b, W1b, W2b, W3b, bp,
                                                              m0, m1, side_dst, side_part);
    fixup_kernel<<<2 * NWIN, 128, 0, stream>>>(Sarr, side_dst, side_part, m0, m1);
    lstm_kernel<<<CELLS / 64, 512, 0, stream>>>(step, xb, m0, m1, h, rc, Wcb, swp, (float*)d_out);
  }
}